// Round 18
// baseline (77.902 us; speedup 1.0000x reference)
//
#include <hip/hip_runtime.h>
#include <hip/hip_bf16.h>
#include <math.h>

// Leapfrog on SPD(32), eigh-free, inverse-free, barrier-free MFMA version.
//   U = S·P ; Ut = P·S (independent) ; H = U·U (= S·P·S·P = S·G)
//   M = 0.02·U - 2e-4·H  (= 2DT·S·pi_half)
//   E = exp(M^T) Taylor-3 (first stage f32 VALU: X3 = I + M/3)
//   Sigma_new = sym(S·E) + 1e-8 I
// TWO matrices per wave, loads for BOTH issued up front (doubles per-wave
// HBM bytes-in-flight — Little's-law analysis: only ~1.8 of 12 waves/CU
// are in load phase, BW-limited at 4.1 of 6.3 TB/s). Compute sequential
// per matrix; same per-wave LDS bounce region with THREE ordering fences:
//   m0 bounce-writes -> fence -> m0 reads -> fence -> m1 writes -> fence -> m1 reads.
// This is R7/R8's memory pattern with its race closed: the bounce reads
// consume OTHER lanes' writes, invisible to per-thread alias analysis ->
// compiler may reorder; R15 proved the class, R16's fence fixed it, and
// R7/R8's rounding-independent 0.09375 was the region-reuse variant.
// All validated pieces: trunc v_perm packs, LDS-bounce sym epilogue with
// contiguous nt stores, cached loads, U^2-head, Taylor-3 f32 first stage,
// independent 3-chain tail, v_permlane32_swap_b32 (swap32(x,y):
// x.lanes[32:63] <-> y.lanes[0:31]), no setprio, no launch-bounds cap
// (R16: forced VGPR cap -> +400MB scratch).

typedef unsigned int u32;
typedef __attribute__((ext_vector_type(8))) short bf16x8;
typedef __attribute__((ext_vector_type(16))) float f32x16;

#define FPAD 33   // f32 row stride of sym buffer: 33 mod 32 == 1 -> conflict-free

union U4 { u32 u[4]; bf16x8 v; };

__device__ __forceinline__ bf16x8 mk8(u32 a, u32 b, u32 c, u32 d) {
    U4 t; t.u[0] = a; t.u[1] = b; t.u[2] = c; t.u[3] = d; return t.v;
}

// pack bf16(x),bf16(y) (truncated) into one u32: low16 = x, high16 = y
__device__ __forceinline__ u32 pkt(float x, float y) {
    return __builtin_amdgcn_perm(__float_as_uint(y), __float_as_uint(x), 0x07060302u);
}

__device__ __forceinline__ float asfloat(u32 b) {
    union { u32 u; float f; } c; c.u = b; return c.f;
}

__device__ __forceinline__ f32x16 zero16() {
    f32x16 z;
#pragma unroll
    for (int i = 0; i < 16; ++i) z[i] = 0.f;
    return z;
}

struct Frag8 { u32 r[8]; };

// v_permlane32_swap_b32: x.lanes[32:63] <-> y.lanes[0:31]
__device__ __forceinline__ void swap32(u32& x, u32& y) {
    asm("v_permlane32_swap_b32 %0, %1" : "+v"(x), "+v"(y));
}

// packed-pair regs p[8] (D-layout pairs) -> B-fragment order.
__device__ __forceinline__ void xchg(const u32* p, Frag8& B) {
    { u32 x = p[0], y = p[2]; swap32(x, y); B.r[0] = x; B.r[2] = y; }
    { u32 x = p[1], y = p[3]; swap32(x, y); B.r[1] = x; B.r[3] = y; }
    { u32 x = p[4], y = p[6]; swap32(x, y); B.r[4] = x; B.r[6] = y; }
    { u32 x = p[5], y = p[7]; swap32(x, y); B.r[5] = x; B.r[7] = y; }
}

__device__ __forceinline__ void bconv(const f32x16& X, Frag8& B) {
    u32 p[8];
#pragma unroll
    for (int i = 0; i < 8; ++i) p[i] = pkt(X[2*i], X[2*i+1]);
    xchg(p, B);
}

__device__ __forceinline__ void bconv_s(const f32x16& X, float scale, Frag8& B) {
    u32 p[8];
#pragma unroll
    for (int i = 0; i < 8; ++i) p[i] = pkt(X[2*i] * scale, X[2*i+1] * scale);
    xchg(p, B);
}

__device__ __forceinline__ void bconv_split(const f32x16& X, Frag8& Bh, Frag8& Bl) {
    u32 p[8], q[8];
#pragma unroll
    for (int i = 0; i < 8; ++i) {
        const float x = X[2*i], y = X[2*i+1];
        p[i] = pkt(x, y);
        const float lx = x - asfloat(p[i] << 16);
        const float ly = y - asfloat(p[i] & 0xffff0000u);
        q[i] = pkt(lx, ly);
    }
    xchg(p, Bh);
    xchg(q, Bl);
}

__device__ __forceinline__ f32x16 MFMA1(const u32* a, const u32* b, f32x16 acc) {
    return __builtin_amdgcn_mfma_f32_32x32x16_bf16(
        mk8(a[0], a[1], a[2], a[3]), mk8(b[0], b[1], b[2], b[3]), acc, 0, 0, 0);
}

__device__ __forceinline__ f32x16 matmul(const Frag8& A, const Frag8& B, f32x16 acc) {
    acc = MFMA1(A.r,     B.r,     acc);   // k = 0..15
    acc = MFMA1(A.r + 4, B.r + 4, acc);   // k = 16..31
    return acc;
}

// full per-matrix compute + epilogue (R14 body). Caller provides the raw
// float4 rows; fences around the LDS bounce are INSIDE (write->read), the
// read->next-matrix-write fence is at the call site.
__device__ __forceinline__ void do_matrix(const float4* sv, const float4* pv,
                                          float phc, float qhc, int bn,
                                          int fr, int h, int l,
                                          float* __restrict__ sy,
                                          const f32x16& If,
                                          float* __restrict__ out)
{
    Frag8 FS, FSl, FP;
#pragma unroll
    for (int i = 0; i < 4; ++i) {
        const float4 s = sv[i];
        const float4 p = pv[i];
        const u32 ha = pkt(s.x, s.y);
        const u32 hb = pkt(s.z, s.w);
        FS.r[2*i]   = ha;
        FS.r[2*i+1] = hb;
        const float lx = s.x - asfloat(ha << 16);
        const float ly = s.y - asfloat(ha & 0xffff0000u);
        const float lz = s.z - asfloat(hb << 16);
        const float lw = s.w - asfloat(hb & 0xffff0000u);
        FSl.r[2*i]   = pkt(lx, ly);
        FSl.r[2*i+1] = pkt(lz, lw);
        FP.r[2*i]   = pkt(p.x, p.y);
        FP.r[2*i+1] = pkt(p.z, p.w);
    }

    // ---- U = S·P ; Ut = P·S (independent) ; H = U·U = S·P·S·P ----
    f32x16 U  = matmul(FS, FP, zero16());
    f32x16 Ut = matmul(FP, FS, zero16());
    Frag8 BU;  bconv(U,  BU);
    Frag8 BUt; bconv(Ut, BUt);              // as A-operand represents U
    f32x16 H = matmul(BUt, BU, zero16());

    // ---- M = 2DT·U − 2DT²·H ;  X3 = I + M/3 (f32 VALU) ----
    f32x16 M, X;
#pragma unroll
    for (int i = 0; i < 16; ++i) {
        M[i] = 0.02f * U[i] - 2e-4f * H[i];
        X[i] = If[i] + (1.0f / 3.0f) * M[i];
    }
    Frag8 FM; bconv(M, FM);                 // A-frag of M^T

    // ---- X2 = I + (1/2)·M^T·X3 ; X1 = I + M^T·X2 ----
    {
        Frag8 BX; bconv_s(X, 0.5f, BX);
        X = matmul(FM, BX, If);
    }
    {
        Frag8 BX; bconv(X, BX);
        X = matmul(FM, BX, If);
    }

    // ---- Y^T = S·X, hi/lo split, three independent 2-MFMA chains ----
    Frag8 BE, BEl;
    bconv_split(X, BE, BEl);
    f32x16 Y1 = matmul(FS,  BE,  zero16());
    f32x16 Y2 = matmul(FSl, BE,  zero16());
    f32x16 Y3 = matmul(FS,  BEl, zero16());

    // ---- sym + eps·I via LDS bounce (fence: writes before reads) ----
#pragma unroll
    for (int i = 0; i < 16; ++i) {
        const int r = (i & 3) + 8 * (i >> 2) + 4 * h;
        sy[r * FPAD + fr] = Y1[i] + Y2[i] + Y3[i];
    }
    __threadfence_block();
    const size_t obase = (size_t)bn * 1027;
#pragma unroll
    for (int k = 0; k < 16; ++k) {
        const int idx = k * 64 + l;
        const int r = idx >> 5, c = idx & 31;
        const float a = sy[r * FPAD + c];
        const float b = sy[c * FPAD + r];
        float v = 0.5f * (a + b);
        if (r == c) v += 1e-8f;
        __builtin_nontemporal_store(v, &out[obase + idx]);
    }

    // ---- phi retraction (lanes 0-2, double; floor-based mod 2pi) ----
    if (l < 3) {
        const double TWO_PI = 6.283185307179586476925287;
        const double PI_    = 3.141592653589793238462643;
        const double c0 = (double)__shfl(phc, 0, 64) + 0.01 * (double)__shfl(qhc, 0, 64);
        const double c1 = (double)__shfl(phc, 1, 64) + 0.01 * (double)__shfl(qhc, 1, 64);
        const double c2 = (double)__shfl(phc, 2, 64) + 0.01 * (double)__shfl(qhc, 2, 64);
        const double me = (l == 0) ? c0 : (l == 1) ? c1 : c2;
        const double theta = sqrt(c0 * c0 + c1 * c1 + c2 * c2);
        const double ts = theta > 1e-12 ? theta : 1e-12;
        const double k2 = floor(theta * (1.0 / TWO_PI));
        const double tw = theta - k2 * TWO_PI;
        double t, sgn;
        if (tw > PI_) { t = TWO_PI - tw; sgn = -1.0; }
        else          { t = tw;          sgn = 1.0;  }
        const double rmax = PI_ - 0.01;
        if (t > rmax) t = rmax;
        const double f = sgn * t / ts;
        __builtin_nontemporal_store((float)(me * f), &out[obase + 1024 + l]);
    }
}

__global__ __launch_bounds__(256)
void leapfrog_fused(const float* __restrict__ Sg, const float* __restrict__ Pg,
                    const float* __restrict__ phig, const float* __restrict__ piphig,
                    float* __restrict__ out, int total)
{
    __shared__ __align__(16) float symb[4 * 32 * FPAD];

    const int w   = threadIdx.x >> 6;
    const int l   = threadIdx.x & 63;
    const int bn0 = blockIdx.x * 8 + w * 2;
    if (bn0 >= total) return;           // wave-uniform; no barriers
    const int bn1  = bn0 + 1;
    const bool has1 = (bn1 < total);
    const int bn1s  = has1 ? bn1 : bn0; // safe address for the dummy load

    float* sy = symb + w * 32 * FPAD;

    const int fr = l & 31;
    const int h  = l >> 5;

    // ---- ALL loads issued up front: 16 float4 + phi for both matrices ----
    const size_t g0 = (size_t)bn0 * 1024;
    const size_t g1 = (size_t)bn1s * 1024;
    const float* S0 = Sg + g0 + fr * 32 + h * 8;
    const float* P0 = Pg + g0 + fr * 32 + h * 8;
    const float* S1 = Sg + g1 + fr * 32 + h * 8;
    const float* P1 = Pg + g1 + fr * 32 + h * 8;
    float4 s0v[4], p0v[4], s1v[4], p1v[4];
    s0v[0] = *(const float4*)(S0 +  0); s0v[1] = *(const float4*)(S0 +  4);
    s0v[2] = *(const float4*)(S0 + 16); s0v[3] = *(const float4*)(S0 + 20);
    p0v[0] = *(const float4*)(P0 +  0); p0v[1] = *(const float4*)(P0 +  4);
    p0v[2] = *(const float4*)(P0 + 16); p0v[3] = *(const float4*)(P0 + 20);
    s1v[0] = *(const float4*)(S1 +  0); s1v[1] = *(const float4*)(S1 +  4);
    s1v[2] = *(const float4*)(S1 + 16); s1v[3] = *(const float4*)(S1 + 20);
    p1v[0] = *(const float4*)(P1 +  0); p1v[1] = *(const float4*)(P1 +  4);
    p1v[2] = *(const float4*)(P1 + 16); p1v[3] = *(const float4*)(P1 + 20);
    float ph0 = 0.f, qh0 = 0.f, ph1 = 0.f, qh1 = 0.f;
    if (l < 3) {
        ph0 = phig[3 * bn0 + l];  qh0 = piphig[3 * bn0 + l];
        ph1 = phig[3 * bn1s + l]; qh1 = piphig[3 * bn1s + l];
    }

    // identity in D-layout: row (i&3)+8*(i>>2)+4h, col fr (shared)
    f32x16 If;
#pragma unroll
    for (int i = 0; i < 16; ++i)
        If[i] = (((i & 3) + 8 * (i >> 2) + 4 * h) == fr) ? 1.f : 0.f;

    // ---- matrix 0 (m1's loads remain in flight underneath) ----
    do_matrix(s0v, p0v, ph0, qh0, bn0, fr, h, l, sy, If, out);

    if (has1) {
        // order m0's bounce READS before m1's bounce WRITES (same region;
        // this missing fence was R7/R8's rounding-independent failure)
        __threadfence_block();
        do_matrix(s1v, p1v, ph1, qh1, bn1, fr, h, l, sy, If, out);
    }
}

extern "C" void kernel_launch(void* const* d_in, const int* in_sizes, int n_in,
                              void* d_out, int out_size, void* d_ws, size_t ws_size,
                              hipStream_t stream)
{
    const float* Sg     = (const float*)d_in[0];
    const float* Pg     = (const float*)d_in[1];
    const float* phig   = (const float*)d_in[2];
    const float* piphig = (const float*)d_in[3];
    float* out = (float*)d_out;

    const int total = in_sizes[0] / 1024;   // B*N = 32768 matrices

    leapfrog_fused<<<(total + 7) / 8, 256, 0, stream>>>(Sg, Pg, phig, piphig, out, total);
}